// Round 2
// baseline (3197.110 us; speedup 1.0000x reference)
//
#include <hip/hip_runtime.h>
#include <math.h>

static inline int cdiv(int a, int b) { return (a + b - 1) / b; }

// ---------------- CSR build ----------------

__global__ __launch_bounds__(256) void k_deg_hist(const int* __restrict__ ei, int E,
                                                  int* __restrict__ deg, int* __restrict__ cnt) {
    int e = blockIdx.x * 256 + threadIdx.x;
    if (e >= E) return;
    int s = ei[e], d = ei[E + e];
    if (s != d) atomicAdd(&deg[s], 1);
    atomicAdd(&cnt[d], 1);
}

__global__ __launch_bounds__(1024) void k_scan(const int* __restrict__ cnt, int* __restrict__ row_ptr,
                                               int N, int E) {
    __shared__ int part[1024];
    int t = threadIdx.x;
    int chunk = (N + 1023) / 1024;
    int beg = t * chunk;
    int end = beg + chunk; if (end > N) end = N;
    int s = 0;
    for (int i = beg; i < end; i++) s += cnt[i];
    part[t] = s;
    __syncthreads();
    for (int off = 1; off < 1024; off <<= 1) {
        int v = (t >= off) ? part[t - off] : 0;
        __syncthreads();
        part[t] += v;
        __syncthreads();
    }
    int base = (t > 0) ? part[t - 1] : 0;
    for (int i = beg; i < end; i++) { row_ptr[i] = base; base += cnt[i]; }
    if (t == 1023) row_ptr[N] = E;
}

__global__ __launch_bounds__(256) void k_scatter(const int* __restrict__ ei, int E,
                                                 const int* __restrict__ deg,
                                                 const int* __restrict__ row_ptr,
                                                 int* __restrict__ fill, int2* __restrict__ csr) {
    int e = blockIdx.x * 256 + threadIdx.x;
    if (e >= E) return;
    int s = ei[e], d = ei[E + e];
    float v = 0.f;
    if (s != d) {
        int a = deg[s], b = deg[d];
        float fa = (a > 0) ? 1.f / sqrtf((float)a) : 0.f;
        float fb = (b > 0) ? 1.f / sqrtf((float)b) : 0.f;
        v = -fa * fb;
    }
    int pos = row_ptr[d] + atomicAdd(&fill[d], 1);
    if (pos < E) csr[pos] = make_int2(s, __float_as_int(v));  // guard: never write OOB
}

// ---------------- propagation: out[n,:] = sum_{e->n} norm_e * h[src_e,:]  (optionally 2*acc - tm2) --------

__global__ __launch_bounds__(256) void k_prop(const float* __restrict__ h, float* __restrict__ out,
                                              const float* __restrict__ tm2,
                                              const int* __restrict__ row_ptr,
                                              const int2* __restrict__ csr, int C) {
    int n = blockIdx.x;
    int t = threadIdx.x;
    int beg = row_ptr[n], end = row_ptr[n + 1];
    if (t >= C) return;
    float acc = 0.f;
    for (int j = beg; j < end; j++) {
        int2 ev = csr[j];
        acc += __int_as_float(ev.y) * h[ev.x * C + t];
    }
    float r = acc;
    if (tm2) r = 2.f * acc - tm2[n * C + t];
    out[n * C + t] = r;
}

// ---------------- fp32 tiled GEMM: Y(+)= X @ W (+bias) ----------------

#define BM 64
#define BN 64
#define BK 16

__global__ __launch_bounds__(256) void k_gemm(const float* __restrict__ X, const float* __restrict__ W,
                                              const float* __restrict__ bias, float* __restrict__ Y,
                                              int M, int Cin, int Cout, int accum) {
    __shared__ float As[BK][BM + 4];
    __shared__ float Bs[BK][BN + 4];
    const int tid = threadIdx.x;
    const int bm = blockIdx.y * BM, bn = blockIdx.x * BN;
    const int tr = tid >> 4, tc = tid & 15;
    const int ar = tid >> 2;           // 0..63
    const int ak = (tid & 3) << 2;     // 0,4,8,12
    const int bk = tid >> 4;           // 0..15
    const int bc = (tid & 15) << 2;    // 0..60
    float acc[4][4] = {};
    for (int k0 = 0; k0 < Cin; k0 += BK) {
        int grow = bm + ar;
#pragma unroll
        for (int u = 0; u < 4; u++) {
            int gk = k0 + ak + u;
            As[ak + u][ar] = (grow < M && gk < Cin) ? X[(size_t)grow * Cin + gk] : 0.f;
        }
        int gkb = k0 + bk;
#pragma unroll
        for (int u = 0; u < 4; u++) {
            int gc = bn + bc + u;
            Bs[bk][bc + u] = (gkb < Cin && gc < Cout) ? W[(size_t)gkb * Cout + gc] : 0.f;
        }
        __syncthreads();
#pragma unroll
        for (int kk = 0; kk < BK; kk++) {
            float a[4], b[4];
#pragma unroll
            for (int i = 0; i < 4; i++) a[i] = As[kk][tr * 4 + i];
#pragma unroll
            for (int j = 0; j < 4; j++) b[j] = Bs[kk][tc * 4 + j];
#pragma unroll
            for (int i = 0; i < 4; i++)
#pragma unroll
                for (int j = 0; j < 4; j++) acc[i][j] += a[i] * b[j];
        }
        __syncthreads();
    }
#pragma unroll
    for (int i = 0; i < 4; i++) {
        int row = bm + tr * 4 + i;
        if (row >= M) continue;
#pragma unroll
        for (int j = 0; j < 4; j++) {
            int col = bn + tc * 4 + j;
            if (col >= Cout) continue;
            float v = acc[i][j];
            if (bias) v += bias[col];
            if (accum) v += Y[(size_t)row * Cout + col];
            Y[(size_t)row * Cout + col] = v;
        }
    }
}

// ---------------- GraphNorm ----------------

__global__ __launch_bounds__(256) void k_stats(const float* __restrict__ Y, float* __restrict__ stats,
                                               int N, int C) {
    int c = threadIdx.x;
    if (c >= C) return;
    float s = 0.f, s2 = 0.f;
    for (int n = blockIdx.x; n < N; n += gridDim.x) {
        float v = Y[(size_t)n * C + c];
        s += v; s2 += v * v;
    }
    atomicAdd(&stats[c], s);
    atomicAdd(&stats[C + c], s2);
}

__global__ __launch_bounds__(256) void k_coeffs(const float* __restrict__ stats,
                                                const float* __restrict__ w, const float* __restrict__ b,
                                                const float* __restrict__ ms,
                                                float* __restrict__ coeffs, int N, int C) {
    int c = threadIdx.x;
    if (c >= C) return;
    float m = stats[c] / (float)N;
    float q = stats[C + c] / (float)N;
    float msv = ms[c];
    float v = q - m * m * msv * (2.f - msv);
    float sc = w[c] / sqrtf(v + 1e-5f);
    coeffs[c] = sc;
    coeffs[C + c] = b[c] - sc * m * msv;
}

// act: 0 = leaky(0.2), 1 = relu
__global__ __launch_bounds__(256) void k_act(const float* __restrict__ Y, float* __restrict__ h,
                                             const float* __restrict__ coeffs, int C, int act) {
    int n = blockIdx.x;
    int c = threadIdx.x;
    if (c >= C) return;
    float v = Y[(size_t)n * C + c];
    if (coeffs) v = v * coeffs[c] + coeffs[C + c];
    if (act == 0) v = (v > 0.f) ? v : 0.2f * v;
    else v = fmaxf(v, 0.f);
    h[(size_t)n * C + c] = v;
}

// ---------------- pooling + head ----------------

__global__ __launch_bounds__(128) void k_pool(const float* __restrict__ h, const int* __restrict__ batch,
                                              float* __restrict__ pooled, float* __restrict__ cntg, int N) {
    int n = blockIdx.x;
    int c = threadIdx.x;
    int b = batch[n];
    atomicAdd(&pooled[b * 128 + c], h[(size_t)n * 128 + c]);
    if (c == 0) atomicAdd(&cntg[b], 1.f);
}

__global__ __launch_bounds__(128) void k_head(const float* __restrict__ pooled, const float* __restrict__ cntg,
                                              const float* __restrict__ W1, const float* __restrict__ b1,
                                              const float* __restrict__ W2, const float* __restrict__ b2,
                                              float* __restrict__ out) {
    __shared__ float p[128];
    __shared__ float h1[64];
    int g = blockIdx.x;
    int t = threadIdx.x;
    float c = cntg[g];
    if (c < 1.f) c = 1.f;
    p[t] = pooled[g * 128 + t] / c;
    __syncthreads();
    if (t < 64) {
        float s = b1[t];
        for (int i = 0; i < 128; i++) s += p[i] * W1[i * 64 + t];
        h1[t] = tanhf(s);
    }
    __syncthreads();
    if (t < 10) {
        float s = b2[t];
        for (int i = 0; i < 64; i++) s += h1[i] * W2[i * 10 + t];
        out[g * 10 + t] = s;
    }
}

// ---------------- orchestration ----------------

extern "C" void kernel_launch(void* const* d_in, const int* in_sizes, int n_in,
                              void* d_out, int out_size, void* d_ws, size_t ws_size,
                              hipStream_t stream) {
    const float* x = (const float*)d_in[0];
    const int* ei = (const int*)d_in[1];
    const int* batch = (const int*)d_in[2];
    const float* convW[6]; const float* convB[6];
    for (int i = 0; i < 6; i++) { convW[i] = (const float*)d_in[3 + 2 * i]; convB[i] = (const float*)d_in[4 + 2 * i]; }
    const float* bnW[4]; const float* bnB[4]; const float* bnMS[4];
    for (int i = 0; i < 4; i++) { bnW[i] = (const float*)d_in[15 + 3 * i]; bnB[i] = (const float*)d_in[16 + 3 * i]; bnMS[i] = (const float*)d_in[17 + 3 * i]; }
    const float* lin1w = (const float*)d_in[27]; const float* lin1b = (const float*)d_in[28];
    const float* lin2w = (const float*)d_in[29]; const float* lin2b = (const float*)d_in[30];
    float* out = (float*)d_out;

    const int N = in_sizes[0] / 128;
    const int E = in_sizes[1] / 2;
    const int G = out_size / 10;

    char* p = (char*)d_ws;
    auto alloc = [&](size_t bytes) -> void* { void* r = (void*)p; p += (bytes + 255) & ~(size_t)255; return r; };
    float* A0 = (float*)alloc((size_t)N * 256 * 4);
    float* A1 = (float*)alloc((size_t)N * 256 * 4);
    float* Yb = (float*)alloc((size_t)N * 256 * 4);
    int2* csr = (int2*)alloc((size_t)E * 8);
    int* row_ptr = (int*)alloc((size_t)(N + 1) * 4);
    int* deg3 = (int*)alloc((size_t)N * 3 * 4);   // deg | cnt | fill, contiguous (no padding between)
    int* deg = deg3;
    int* cnt = deg3 + N;
    int* fill = deg3 + 2 * N;
    float* stats = (float*)alloc(512 * 4);
    float* coeffs = (float*)alloc(512 * 4);
    float* pooled = (float*)alloc((size_t)G * 128 * 4);
    float* cntg = (float*)alloc((size_t)G * 4);

    hipMemsetAsync(deg3, 0, (size_t)N * 3 * 4, stream);   // covers deg, cnt, fill exactly
    k_deg_hist<<<cdiv(E, 256), 256, 0, stream>>>(ei, E, deg, cnt);
    k_scan<<<1, 1024, 0, stream>>>(cnt, row_ptr, N, E);
    k_scatter<<<cdiv(E, 256), 256, 0, stream>>>(ei, E, deg, row_ptr, fill, csr);

    struct LayerDef { int K, Cin, Cout, bn, act; };
    const LayerDef L[6] = {
        {2, 128, 190, 0, 0},
        {2, 190, 256, 1, 0},
        {2, 256, 169, 2, 0},
        {5, 169, 190, -1, 1},
        {1, 190, 256, -1, 1},
        {3, 256, 128, 3, 0},
    };

    const float* hin = x;
    for (int li = 0; li < 6; li++) {
        const int K = L[li].K, Cin = L[li].Cin, Cout = L[li].Cout;
        dim3 gg(cdiv(Cout, BN), cdiv(N, BM));
        // term 0
        k_gemm<<<gg, 256, 0, stream>>>(hin, convW[li], convB[li], Yb, N, Cin, Cout, 0);
        if (K > 1) {
            // T1 = prop(T0)
            k_prop<<<N, 256, 0, stream>>>(hin, A1, nullptr, row_ptr, csr, Cin);
            k_gemm<<<gg, 256, 0, stream>>>(A1, convW[li] + (size_t)Cin * Cout, nullptr, Yb, N, Cin, Cout, 1);
            // T_k = 2*prop(T_{k-1}) - T_{k-2}, written in place over T_{k-2}'s buffer.
            // For li>0, hin == A0, so the rotation is A1 -> A0 -> A1 -> ...
            const float* tin = A1;
            float* tout = A0;
            for (int k = 2; k < K; k++) {
                k_prop<<<N, 256, 0, stream>>>(tin, tout, tout, row_ptr, csr, Cin);
                k_gemm<<<gg, 256, 0, stream>>>(tout, convW[li] + (size_t)k * Cin * Cout, nullptr, Yb, N, Cin, Cout, 1);
                const float* t = tin; tin = tout; tout = (float*)t;
            }
        }
        // norm + act -> A0 (next layer input)
        if (L[li].bn >= 0) {
            hipMemsetAsync(stats, 0, 512 * 4, stream);
            k_stats<<<256, 256, 0, stream>>>(Yb, stats, N, Cout);
            k_coeffs<<<1, 256, 0, stream>>>(stats, bnW[L[li].bn], bnB[L[li].bn], bnMS[L[li].bn], coeffs, N, Cout);
            k_act<<<N, 256, 0, stream>>>(Yb, A0, coeffs, Cout, 0);
        } else {
            k_act<<<N, 256, 0, stream>>>(Yb, A0, nullptr, Cout, 1);
        }
        hin = A0;
    }

    hipMemsetAsync(pooled, 0, (size_t)G * 128 * 4, stream);
    hipMemsetAsync(cntg, 0, (size_t)G * 4, stream);
    k_pool<<<N, 128, 0, stream>>>(A0, batch, pooled, cntg, N);
    k_head<<<G, 128, 0, stream>>>(pooled, cntg, lin1w, lin1b, lin2w, lin2b, out);
}

// Round 3
// 2022.005 us; speedup vs baseline: 1.5812x; 1.5812x over previous
//
#include <hip/hip_runtime.h>
#include <math.h>

static inline int cdiv(int a, int b) { return (a + b - 1) / b; }

typedef __attribute__((ext_vector_type(8))) short short8;
typedef __attribute__((ext_vector_type(4))) float floatx4;

__device__ inline unsigned short f2bf(float f) {
    unsigned int u = __float_as_uint(f);
    unsigned int r = (u + 0x7fffu + ((u >> 16) & 1u)) >> 16;
    return (unsigned short)r;
}

// ---------------- CSR build ----------------

__global__ __launch_bounds__(256) void k_deg_hist(const int* __restrict__ ei, int E,
                                                  int* __restrict__ deg, int* __restrict__ cnt) {
    int e = blockIdx.x * 256 + threadIdx.x;
    if (e >= E) return;
    int s = ei[e], d = ei[E + e];
    if (s != d) atomicAdd(&deg[s], 1);
    atomicAdd(&cnt[d], 1);
}

__global__ __launch_bounds__(1024) void k_scan(const int* __restrict__ cnt, int* __restrict__ row_ptr,
                                               int N, int E) {
    __shared__ int part[1024];
    int t = threadIdx.x;
    int chunk = (N + 1023) / 1024;
    int beg = t * chunk;
    int end = beg + chunk; if (end > N) end = N;
    int s = 0;
    for (int i = beg; i < end; i++) s += cnt[i];
    part[t] = s;
    __syncthreads();
    for (int off = 1; off < 1024; off <<= 1) {
        int v = (t >= off) ? part[t - off] : 0;
        __syncthreads();
        part[t] += v;
        __syncthreads();
    }
    int base = (t > 0) ? part[t - 1] : 0;
    for (int i = beg; i < end; i++) { row_ptr[i] = base; base += cnt[i]; }
    if (t == 1023) row_ptr[N] = E;
}

__global__ __launch_bounds__(256) void k_scatter(const int* __restrict__ ei, int E,
                                                 const int* __restrict__ deg,
                                                 const int* __restrict__ row_ptr,
                                                 int* __restrict__ fill, int2* __restrict__ csr) {
    int e = blockIdx.x * 256 + threadIdx.x;
    if (e >= E) return;
    int s = ei[e], d = ei[E + e];
    float v = 0.f;
    if (s != d) {
        int a = deg[s], b = deg[d];
        float fa = (a > 0) ? 1.f / sqrtf((float)a) : 0.f;
        float fb = (b > 0) ? 1.f / sqrtf((float)b) : 0.f;
        v = -fa * fb;
    }
    int pos = row_ptr[d] + atomicAdd(&fill[d], 1);
    if (pos < E) csr[pos] = make_int2(s, __float_as_int(v));
}

// ---------------- weight convert: W[K][Cout] fp32 -> WT[term][Cout][ldk] bf16 (k zero-padded) -----

__global__ __launch_bounds__(256) void k_wconv(const float* __restrict__ W, unsigned short* __restrict__ WT,
                                               int Cin, int Cout, int ldk, int total) {
    int idx = blockIdx.x * 256 + threadIdx.x;
    if (idx >= total) return;
    int per_term = Cout * ldk;
    int term = idx / per_term;
    int rem = idx - term * per_term;
    int n = rem / ldk;
    int k = rem - n * ldk;
    float v = (k < Cin) ? W[(size_t)term * Cin * Cout + (size_t)k * Cout + n] : 0.f;
    WT[idx] = f2bf(v);
}

// ---------------- propagation: wave per node, float4 gather ----------------
// out[n][0:C] = sum_e norm_e * h[src_e][0:C];  optionally r = 2*acc - tm2.  out stride 256 floats.

__global__ __launch_bounds__(256) void k_prop4(const float* __restrict__ h, int ld4in,
                                               float* __restrict__ out, const float* __restrict__ tm2,
                                               const int* __restrict__ row_ptr,
                                               const int2* __restrict__ csr, int C4, int Nn) {
    int node = (blockIdx.x << 2) + (threadIdx.x >> 6);
    if (node >= Nn) return;
    int lane = threadIdx.x & 63;
    if (lane >= C4) return;
    int beg = row_ptr[node], end = row_ptr[node + 1];
    const float4* h4 = (const float4*)h;
    float ax = 0.f, ay = 0.f, az = 0.f, aw = 0.f;
    int j = beg;
    for (; j + 2 <= end; j += 2) {
        int2 e0 = csr[j];
        int2 e1 = csr[j + 1];
        float4 v0 = h4[(size_t)e0.x * ld4in + lane];
        float4 v1 = h4[(size_t)e1.x * ld4in + lane];
        float n0 = __int_as_float(e0.y), n1 = __int_as_float(e1.y);
        ax += n0 * v0.x + n1 * v1.x;
        ay += n0 * v0.y + n1 * v1.y;
        az += n0 * v0.z + n1 * v1.z;
        aw += n0 * v0.w + n1 * v1.w;
    }
    if (j < end) {
        int2 e0 = csr[j];
        float4 v0 = h4[(size_t)e0.x * ld4in + lane];
        float n0 = __int_as_float(e0.y);
        ax += n0 * v0.x; ay += n0 * v0.y; az += n0 * v0.z; aw += n0 * v0.w;
    }
    float4 r = make_float4(ax, ay, az, aw);
    if (tm2) {
        float4 t = ((const float4*)tm2)[(size_t)node * 64 + lane];
        r.x = 2.f * ax - t.x; r.y = 2.f * ay - t.y; r.z = 2.f * az - t.z; r.w = 2.f * aw - t.w;
    }
    ((float4*)out)[(size_t)node * 64 + lane] = r;
}

// ---------------- bf16 MFMA GEMM: Y(+)= X(fp32,ldx) @ WT^T (+bias), Y stride 256 ----------------
// Tile: BM=256, BN=64, BK=32. 256 threads = 4 waves; wave w owns rows [64w,64w+64) x 64 cols,
// as 4x4 grid of 16x16x32 MFMA fragments.

__global__ __launch_bounds__(256, 2) void k_gemm_mfma(const float* __restrict__ X, int ldx,
                                                      const unsigned short* __restrict__ WT, int ldk,
                                                      const float* __restrict__ bias,
                                                      float* __restrict__ Y,
                                                      int M, int Cin, int Cout, int accum) {
    __shared__ unsigned short As[256][40];
    __shared__ unsigned short Bs[64][40];
    const int t = threadIdx.x;
    const int bm = blockIdx.y * 256, bn = blockIdx.x * 64;
    const int w = t >> 6, lane = t & 63;
    const int fr = lane & 15, fg = lane >> 4;
    // A staging indices: 8 passes, 32 rows/pass, 8 threads per row (float4 each)
    const int arow = t >> 3;          // 0..31
    const int akq = (t & 7) * 4;      // 0,4,...,28
    // B staging indices
    const int brow = t >> 2;          // 0..63
    const int bkq = (t & 3) * 8;      // 0,8,16,24

    floatx4 acc[4][4];
#pragma unroll
    for (int i = 0; i < 4; i++)
#pragma unroll
        for (int j = 0; j < 4; j++) acc[i][j] = (floatx4){0.f, 0.f, 0.f, 0.f};

    for (int k0 = 0; k0 < Cin; k0 += 32) {
        const bool fullk = (k0 + 32 <= Cin);
        // stage A: rows bm..bm+256, k0..k0+32 fp32 -> bf16
#pragma unroll
        for (int p = 0; p < 8; p++) {
            int r = p * 32 + arow;
            int grow = bm + r;
            float4 v = make_float4(0.f, 0.f, 0.f, 0.f);
            if (grow < M) {
                if (fullk) {
                    v = *(const float4*)&X[(size_t)grow * ldx + k0 + akq];
                } else {
                    float tmp[4];
#pragma unroll
                    for (int i = 0; i < 4; i++)
                        tmp[i] = (k0 + akq + i < Cin) ? X[(size_t)grow * ldx + k0 + akq + i] : 0.f;
                    v = make_float4(tmp[0], tmp[1], tmp[2], tmp[3]);
                }
            }
            ushort4 wv;
            wv.x = f2bf(v.x); wv.y = f2bf(v.y); wv.z = f2bf(v.z); wv.w = f2bf(v.w);
            *(ushort4*)&As[r][akq] = wv;
        }
        // stage B: WT rows (cols of W), k pre-padded with zeros
        {
            int gn = bn + brow;
            uint4 wv = make_uint4(0u, 0u, 0u, 0u);
            if (gn < Cout) wv = *(const uint4*)&WT[(size_t)gn * ldk + k0 + bkq];
            *(uint4*)&Bs[brow][bkq] = wv;
        }
        __syncthreads();

        short8 a[4], b[4];
#pragma unroll
        for (int i = 0; i < 4; i++) a[i] = *(const short8*)&As[64 * w + 16 * i + fr][fg * 8];
#pragma unroll
        for (int i = 0; i < 4; i++) b[i] = *(const short8*)&Bs[16 * i + fr][fg * 8];
#pragma unroll
        for (int i = 0; i < 4; i++)
#pragma unroll
            for (int j = 0; j < 4; j++)
                acc[i][j] = __builtin_amdgcn_mfma_f32_16x16x32_bf16(a[i], b[j], acc[i][j], 0, 0, 0);
        __syncthreads();
    }

    // epilogue: C/D layout col=lane&15, row=(lane>>4)*4+q
#pragma unroll
    for (int i = 0; i < 4; i++) {
#pragma unroll
        for (int j = 0; j < 4; j++) {
#pragma unroll
            for (int q = 0; q < 4; q++) {
                int r = bm + 64 * w + 16 * i + fg * 4 + q;
                int c = bn + 16 * j + fr;
                if (r < M && c < Cout) {
                    float v = acc[i][j][q];
                    if (bias) v += bias[c];
                    if (accum) v += Y[(size_t)r * 256 + c];
                    Y[(size_t)r * 256 + c] = v;
                }
            }
        }
    }
}

// ---------------- GraphNorm ----------------

__global__ __launch_bounds__(256) void k_stats(const float* __restrict__ Y, float* __restrict__ stats,
                                               int N, int C) {
    int c = threadIdx.x;
    if (c >= C) return;
    float s = 0.f, s2 = 0.f;
    for (int n = blockIdx.x; n < N; n += gridDim.x) {
        float v = Y[(size_t)n * 256 + c];
        s += v; s2 += v * v;
    }
    atomicAdd(&stats[c], s);
    atomicAdd(&stats[C + c], s2);
}

__global__ __launch_bounds__(256) void k_coeffs(const float* __restrict__ stats,
                                                const float* __restrict__ w, const float* __restrict__ b,
                                                const float* __restrict__ ms,
                                                float* __restrict__ coeffs, int N, int C) {
    int c = threadIdx.x;
    if (c >= C) return;
    float m = stats[c] / (float)N;
    float q = stats[C + c] / (float)N;
    float msv = ms[c];
    float v = q - m * m * msv * (2.f - msv);
    float sc = w[c] / sqrtf(v + 1e-5f);
    coeffs[c] = sc;
    coeffs[C + c] = b[c] - sc * m * msv;
}

// act: 0 = leaky(0.2), 1 = relu
__global__ __launch_bounds__(256) void k_act(const float* __restrict__ Y, float* __restrict__ h,
                                             const float* __restrict__ coeffs, int C, int act) {
    int n = blockIdx.x;
    int c = threadIdx.x;
    if (c >= C) return;
    float v = Y[(size_t)n * 256 + c];
    if (coeffs) v = v * coeffs[c] + coeffs[C + c];
    if (act == 0) v = (v > 0.f) ? v : 0.2f * v;
    else v = fmaxf(v, 0.f);
    h[(size_t)n * 256 + c] = v;
}

// ---------------- pooling (sorted batch -> segmented run reduction) + head ----------------

__global__ __launch_bounds__(128) void k_pool2(const float* __restrict__ h, const int* __restrict__ batch,
                                               float* __restrict__ pooled, float* __restrict__ cntg, int N) {
    int t = threadIdx.x;
    int beg = blockIdx.x * 256;
    int end = beg + 256; if (end > N) end = N;
    int cur = batch[beg];
    float acc = 0.f;
    int runlen = 0;
    for (int n = beg; n < end; n++) {
        int b = batch[n];
        if (b != cur) {
            atomicAdd(&pooled[cur * 128 + t], acc);
            if (t == 0) atomicAdd(&cntg[cur], (float)runlen);
            acc = 0.f; runlen = 0; cur = b;
        }
        acc += h[(size_t)n * 256 + t];
        runlen++;
    }
    atomicAdd(&pooled[cur * 128 + t], acc);
    if (t == 0) atomicAdd(&cntg[cur], (float)runlen);
}

__global__ __launch_bounds__(128) void k_head(const float* __restrict__ pooled, const float* __restrict__ cntg,
                                              const float* __restrict__ W1, const float* __restrict__ b1,
                                              const float* __restrict__ W2, const float* __restrict__ b2,
                                              float* __restrict__ out) {
    __shared__ float p[128];
    __shared__ float h1[64];
    int g = blockIdx.x;
    int t = threadIdx.x;
    float c = cntg[g];
    if (c < 1.f) c = 1.f;
    p[t] = pooled[g * 128 + t] / c;
    __syncthreads();
    if (t < 64) {
        float s = b1[t];
        for (int i = 0; i < 128; i++) s += p[i] * W1[i * 64 + t];
        h1[t] = tanhf(s);
    }
    __syncthreads();
    if (t < 10) {
        float s = b2[t];
        for (int i = 0; i < 64; i++) s += h1[i] * W2[i * 10 + t];
        out[g * 10 + t] = s;
    }
}

// ---------------- orchestration ----------------

extern "C" void kernel_launch(void* const* d_in, const int* in_sizes, int n_in,
                              void* d_out, int out_size, void* d_ws, size_t ws_size,
                              hipStream_t stream) {
    const float* x = (const float*)d_in[0];
    const int* ei = (const int*)d_in[1];
    const int* batch = (const int*)d_in[2];
    const float* convW[6]; const float* convB[6];
    for (int i = 0; i < 6; i++) { convW[i] = (const float*)d_in[3 + 2 * i]; convB[i] = (const float*)d_in[4 + 2 * i]; }
    const float* bnW[4]; const float* bnB[4]; const float* bnMS[4];
    for (int i = 0; i < 4; i++) { bnW[i] = (const float*)d_in[15 + 3 * i]; bnB[i] = (const float*)d_in[16 + 3 * i]; bnMS[i] = (const float*)d_in[17 + 3 * i]; }
    const float* lin1w = (const float*)d_in[27]; const float* lin1b = (const float*)d_in[28];
    const float* lin2w = (const float*)d_in[29]; const float* lin2b = (const float*)d_in[30];
    float* out = (float*)d_out;

    const int N = in_sizes[0] / 128;
    const int E = in_sizes[1] / 2;
    const int G = out_size / 10;

    struct LayerDef { int K, Cin, Cout, bn, ldk; };
    const LayerDef L[6] = {
        {2, 128, 190, 0, 128},
        {2, 190, 256, 1, 192},
        {2, 256, 169, 2, 256},
        {5, 169, 190, -1, 192},
        {1, 190, 256, -1, 192},
        {3, 256, 128, 3, 256},
    };

    char* p = (char*)d_ws;
    auto alloc = [&](size_t bytes) -> void* { void* r = (void*)p; p += (bytes + 255) & ~(size_t)255; return r; };
    float* A0 = (float*)alloc((size_t)N * 256 * 4);
    float* A1 = (float*)alloc((size_t)N * 256 * 4);
    float* Yb = (float*)alloc((size_t)N * 256 * 4);
    int2* csr = (int2*)alloc((size_t)E * 8);
    int* row_ptr = (int*)alloc((size_t)(N + 1) * 4);
    int* deg3 = (int*)alloc((size_t)N * 3 * 4);
    int* deg = deg3;
    int* cnt = deg3 + N;
    int* fill = deg3 + 2 * N;
    float* stats = (float*)alloc(512 * 4);
    float* coeffs = (float*)alloc(512 * 4);
    float* pooled = (float*)alloc((size_t)G * 128 * 4);
    float* cntg = (float*)alloc((size_t)G * 4);
    unsigned short* WT[6];
    for (int i = 0; i < 6; i++) WT[i] = (unsigned short*)alloc((size_t)L[i].K * L[i].Cout * L[i].ldk * 2);

    hipMemsetAsync(deg3, 0, (size_t)N * 3 * 4, stream);
    k_deg_hist<<<cdiv(E, 256), 256, 0, stream>>>(ei, E, deg, cnt);
    k_scan<<<1, 1024, 0, stream>>>(cnt, row_ptr, N, E);
    k_scatter<<<cdiv(E, 256), 256, 0, stream>>>(ei, E, deg, row_ptr, fill, csr);
    for (int i = 0; i < 6; i++) {
        int total = L[i].K * L[i].Cout * L[i].ldk;
        k_wconv<<<cdiv(total, 256), 256, 0, stream>>>(convW[i], WT[i], L[i].Cin, L[i].Cout, L[i].ldk, total);
    }

    const float* hin = x;
    for (int li = 0; li < 6; li++) {
        const int K = L[li].K, Cin = L[li].Cin, Cout = L[li].Cout, ldk = L[li].ldk;
        const int ldh = (li == 0) ? 128 : 256;
        const int C4 = (Cin + 3) / 4;
        dim3 gg(cdiv(Cout, 64), cdiv(N, 256));
        // term 0
        k_gemm_mfma<<<gg, 256, 0, stream>>>(hin, ldh, WT[li], ldk, convB[li], Yb, N, Cin, Cout, 0);
        if (K > 1) {
            // T1 = prop(T0)
            k_prop4<<<cdiv(N, 4), 256, 0, stream>>>(hin, ldh / 4, A1, nullptr, row_ptr, csr, C4, N);
            k_gemm_mfma<<<gg, 256, 0, stream>>>(A1, 256, WT[li] + (size_t)Cout * ldk, ldk, nullptr, Yb, N, Cin, Cout, 1);
            // T_k = 2*prop(T_{k-1}) - T_{k-2} (in place over T_{k-2}'s buffer)
            const float* tin = A1;
            float* tout = A0;
            for (int k = 2; k < K; k++) {
                k_prop4<<<cdiv(N, 4), 256, 0, stream>>>(tin, 64, tout, tout, row_ptr, csr, C4, N);
                k_gemm_mfma<<<gg, 256, 0, stream>>>(tout, 256, WT[li] + (size_t)k * Cout * ldk, ldk, nullptr, Yb, N, Cin, Cout, 1);
                const float* t = tin; tin = tout; tout = (float*)t;
            }
        }
        // norm + act -> A0
        if (L[li].bn >= 0) {
            hipMemsetAsync(stats, 0, 512 * 4, stream);
            k_stats<<<256, 256, 0, stream>>>(Yb, stats, N, Cout);
            k_coeffs<<<1, 256, 0, stream>>>(stats, bnW[L[li].bn], bnB[L[li].bn], bnMS[L[li].bn], coeffs, N, Cout);
            k_act<<<N, 256, 0, stream>>>(Yb, A0, coeffs, Cout, 0);
        } else {
            k_act<<<N, 256, 0, stream>>>(Yb, A0, nullptr, Cout, 1);
        }
        hin = A0;
    }

    hipMemsetAsync(pooled, 0, (size_t)G * 128 * 4, stream);
    hipMemsetAsync(cntg, 0, (size_t)G * 4, stream);
    k_pool2<<<cdiv(N, 256), 128, 0, stream>>>(A0, batch, pooled, cntg, N);
    k_head<<<G, 128, 0, stream>>>(pooled, cntg, lin1w, lin1b, lin2w, lin2b, out);
}

// Round 4
// 1487.808 us; speedup vs baseline: 2.1489x; 1.3590x over previous
//
#include <hip/hip_runtime.h>
#include <math.h>

static inline int cdiv(int a, int b) { return (a + b - 1) / b; }

typedef __attribute__((ext_vector_type(8))) short short8;
typedef __attribute__((ext_vector_type(4))) float floatx4;

__device__ inline unsigned short f2bf(float f) {
    unsigned int u = __float_as_uint(f);
    unsigned int r = (u + 0x7fffu + ((u >> 16) & 1u)) >> 16;
    return (unsigned short)r;
}
__device__ inline float bf2f(unsigned short u) {
    return __uint_as_float(((unsigned int)u) << 16);
}

// ---------------- CSR build ----------------

__global__ __launch_bounds__(256) void k_deg_hist(const int* __restrict__ ei, int E,
                                                  int* __restrict__ deg, int* __restrict__ cnt) {
    int e = blockIdx.x * 256 + threadIdx.x;
    if (e >= E) return;
    int s = ei[e], d = ei[E + e];
    if (s != d) atomicAdd(&deg[s], 1);
    atomicAdd(&cnt[d], 1);
}

__global__ __launch_bounds__(1024) void k_scan(const int* __restrict__ cnt, int* __restrict__ row_ptr,
                                               int N, int E) {
    __shared__ int part[1024];
    int t = threadIdx.x;
    int chunk = (N + 1023) / 1024;
    int beg = t * chunk;
    int end = beg + chunk; if (end > N) end = N;
    int s = 0;
    for (int i = beg; i < end; i++) s += cnt[i];
    part[t] = s;
    __syncthreads();
    for (int off = 1; off < 1024; off <<= 1) {
        int v = (t >= off) ? part[t - off] : 0;
        __syncthreads();
        part[t] += v;
        __syncthreads();
    }
    int base = (t > 0) ? part[t - 1] : 0;
    for (int i = beg; i < end; i++) { row_ptr[i] = base; base += cnt[i]; }
    if (t == 1023) row_ptr[N] = E;
}

__global__ __launch_bounds__(256) void k_scatter(const int* __restrict__ ei, int E,
                                                 const int* __restrict__ deg,
                                                 const int* __restrict__ row_ptr,
                                                 int* __restrict__ fill, int2* __restrict__ csr) {
    int e = blockIdx.x * 256 + threadIdx.x;
    if (e >= E) return;
    int s = ei[e], d = ei[E + e];
    float v = 0.f;
    if (s != d) {
        int a = deg[s], b = deg[d];
        float fa = (a > 0) ? 1.f / sqrtf((float)a) : 0.f;
        float fb = (b > 0) ? 1.f / sqrtf((float)b) : 0.f;
        v = -fa * fb;
    }
    int pos = row_ptr[d] + atomicAdd(&fill[d], 1);
    if (pos < E) csr[pos] = make_int2(s, __float_as_int(v));
}

// ---------------- weight convert: W[K][Cin][Cout] fp32 -> WT[term][Cout][ldk] bf16 (k zero-padded) -----

__global__ __launch_bounds__(256) void k_wconv(const float* __restrict__ W, unsigned short* __restrict__ WT,
                                               int Cin, int Cout, int ldk, int total) {
    int idx = blockIdx.x * 256 + threadIdx.x;
    if (idx >= total) return;
    int per_term = Cout * ldk;
    int term = idx / per_term;
    int rem = idx - term * per_term;
    int n = rem / ldk;
    int k = rem - n * ldk;
    float v = (k < Cin) ? W[(size_t)term * Cin * Cout + (size_t)k * Cout + n] : 0.f;
    WT[idx] = f2bf(v);
}

// ---------------- x (fp32, ld 128) -> bf16 ld 256 ----------------

__global__ __launch_bounds__(256) void k_x0(const float* __restrict__ x, unsigned short* __restrict__ xb, int N) {
    int n = blockIdx.x;
    int c = threadIdx.x;
    if (c < 128) xb[(size_t)n * 256 + c] = f2bf(x[(size_t)n * 128 + c]);
}

// ---------------- propagation (bf16 gather, fp32 accumulate) ----------------
// out[n][0:C] = sum_e norm_e * h[src_e][0:C]; if tm2: r = 2*acc - tm2.  All row strides = 256 elems.
// Wave per node; lane handles 4 channels (ushort4 = 8B gather per lane).

__global__ __launch_bounds__(256) void k_prop_bf(const unsigned short* __restrict__ hb,
                                                 unsigned short* __restrict__ outb,
                                                 float* __restrict__ outf,           // optional fp32 copy
                                                 const unsigned short* __restrict__ tm2b,  // optional bf16 tm2
                                                 const float* __restrict__ tm2f,           // optional fp32 tm2
                                                 const int* __restrict__ row_ptr,
                                                 const int2* __restrict__ csr, int C4, int Nn) {
    int node = (blockIdx.x << 2) + (threadIdx.x >> 6);
    if (node >= Nn) return;
    int lane = threadIdx.x & 63;
    if (lane >= C4) return;
    int beg = row_ptr[node], end = row_ptr[node + 1];
    const ushort4* h4 = (const ushort4*)hb;
    float a0 = 0.f, a1 = 0.f, a2 = 0.f, a3 = 0.f;
    int j = beg;
    for (; j + 2 <= end; j += 2) {
        int2 e0 = csr[j];
        int2 e1 = csr[j + 1];
        ushort4 v0 = h4[(size_t)e0.x * 64 + lane];
        ushort4 v1 = h4[(size_t)e1.x * 64 + lane];
        float n0 = __int_as_float(e0.y), n1 = __int_as_float(e1.y);
        a0 += n0 * bf2f(v0.x) + n1 * bf2f(v1.x);
        a1 += n0 * bf2f(v0.y) + n1 * bf2f(v1.y);
        a2 += n0 * bf2f(v0.z) + n1 * bf2f(v1.z);
        a3 += n0 * bf2f(v0.w) + n1 * bf2f(v1.w);
    }
    if (j < end) {
        int2 e0 = csr[j];
        ushort4 v0 = h4[(size_t)e0.x * 64 + lane];
        float n0 = __int_as_float(e0.y);
        a0 += n0 * bf2f(v0.x); a1 += n0 * bf2f(v0.y); a2 += n0 * bf2f(v0.z); a3 += n0 * bf2f(v0.w);
    }
    if (tm2b) {
        ushort4 t = ((const ushort4*)tm2b)[(size_t)node * 64 + lane];
        a0 = 2.f * a0 - bf2f(t.x); a1 = 2.f * a1 - bf2f(t.y);
        a2 = 2.f * a2 - bf2f(t.z); a3 = 2.f * a3 - bf2f(t.w);
    } else if (tm2f) {
        float4 t = ((const float4*)tm2f)[(size_t)node * 64 + lane];
        a0 = 2.f * a0 - t.x; a1 = 2.f * a1 - t.y; a2 = 2.f * a2 - t.z; a3 = 2.f * a3 - t.w;
    }
    ushort4 r;
    r.x = f2bf(a0); r.y = f2bf(a1); r.z = f2bf(a2); r.w = f2bf(a3);
    ((ushort4*)outb)[(size_t)node * 64 + lane] = r;
    if (outf) ((float4*)outf)[(size_t)node * 64 + lane] = make_float4(a0, a1, a2, a3);
}

// ---------------- bf16 MFMA GEMM: Y(+)= Xb(bf16, ld 256) @ WT^T (+bias), Y fp32 stride 256 ----------
// Tile: BM=256, BN=64, BK=32. 4 waves; wave w owns rows [64w,64w+64) x 64 cols (4x4 of 16x16x32).

__global__ __launch_bounds__(256, 2) void k_gemm_mfma(const unsigned short* __restrict__ Xb,
                                                      const unsigned short* __restrict__ WT, int ldk,
                                                      const float* __restrict__ bias,
                                                      float* __restrict__ Y,
                                                      int M, int Cin, int Cout, int accum) {
    __shared__ unsigned short As[256][40];
    __shared__ unsigned short Bs[64][40];
    const int t = threadIdx.x;
    const int bm = blockIdx.y * 256, bn = blockIdx.x * 64;
    const int w = t >> 6, lane = t & 63;
    const int fr = lane & 15, fg = lane >> 4;
    // A staging: 4 passes, 64 rows/pass, 4 threads/row, 8 bf16 (16B) each
    const int arow = t >> 2;          // 0..63
    const int akq = (t & 3) * 8;      // 0,8,16,24
    // B staging
    const int brow = t >> 2;          // 0..63
    const int bkq = (t & 3) * 8;      // 0,8,16,24

    floatx4 acc[4][4];
#pragma unroll
    for (int i = 0; i < 4; i++)
#pragma unroll
        for (int j = 0; j < 4; j++) acc[i][j] = (floatx4){0.f, 0.f, 0.f, 0.f};

    for (int k0 = 0; k0 < Cin; k0 += 32) {
        const bool fullgrp = (k0 + akq + 8 <= Cin);
        // stage A (bf16 copy, guard k>=Cin with zeros)
#pragma unroll
        for (int p = 0; p < 4; p++) {
            int r = p * 64 + arow;
            int grow = bm + r;
            uint4 wv = make_uint4(0u, 0u, 0u, 0u);
            if (grow < M) {
                if (fullgrp) {
                    wv = *(const uint4*)&Xb[(size_t)grow * 256 + k0 + akq];
                } else {
                    unsigned short tmp[8];
#pragma unroll
                    for (int i = 0; i < 8; i++)
                        tmp[i] = (k0 + akq + i < Cin) ? Xb[(size_t)grow * 256 + k0 + akq + i] : (unsigned short)0;
                    wv = *(uint4*)tmp;
                }
            }
            *(uint4*)&As[r][akq] = wv;
        }
        // stage B: WT rows (cols of W), k pre-padded with zeros
        {
            int gn = bn + brow;
            uint4 wv = make_uint4(0u, 0u, 0u, 0u);
            if (gn < Cout) wv = *(const uint4*)&WT[(size_t)gn * ldk + k0 + bkq];
            *(uint4*)&Bs[brow][bkq] = wv;
        }
        __syncthreads();

        short8 a[4], b[4];
#pragma unroll
        for (int i = 0; i < 4; i++) a[i] = *(const short8*)&As[64 * w + 16 * i + fr][fg * 8];
#pragma unroll
        for (int i = 0; i < 4; i++) b[i] = *(const short8*)&Bs[16 * i + fr][fg * 8];
#pragma unroll
        for (int i = 0; i < 4; i++)
#pragma unroll
            for (int j = 0; j < 4; j++)
                acc[i][j] = __builtin_amdgcn_mfma_f32_16x16x32_bf16(a[i], b[j], acc[i][j], 0, 0, 0);
        __syncthreads();
    }

    // epilogue: C/D layout col=lane&15, row=(lane>>4)*4+q
#pragma unroll
    for (int i = 0; i < 4; i++) {
#pragma unroll
        for (int j = 0; j < 4; j++) {
#pragma unroll
            for (int q = 0; q < 4; q++) {
                int r = bm + 64 * w + 16 * i + fg * 4 + q;
                int c = bn + 16 * j + fr;
                if (r < M && c < Cout) {
                    float v = acc[i][j][q];
                    if (bias) v += bias[c];
                    if (accum) v += Y[(size_t)r * 256 + c];
                    Y[(size_t)r * 256 + c] = v;
                }
            }
        }
    }
}

// ---------------- GraphNorm ----------------

__global__ __launch_bounds__(256) void k_stats(const float* __restrict__ Y, float* __restrict__ stats,
                                               int N, int C) {
    int c = threadIdx.x;
    if (c >= C) return;
    float s = 0.f, s2 = 0.f;
    for (int n = blockIdx.x; n < N; n += gridDim.x) {
        float v = Y[(size_t)n * 256 + c];
        s += v; s2 += v * v;
    }
    atomicAdd(&stats[c], s);
    atomicAdd(&stats[C + c], s2);
}

__global__ __launch_bounds__(256) void k_coeffs(const float* __restrict__ stats,
                                                const float* __restrict__ w, const float* __restrict__ b,
                                                const float* __restrict__ ms,
                                                float* __restrict__ coeffs, int N, int C) {
    int c = threadIdx.x;
    if (c >= C) return;
    float m = stats[c] / (float)N;
    float q = stats[C + c] / (float)N;
    float msv = ms[c];
    float v = q - m * m * msv * (2.f - msv);
    float sc = w[c] / sqrtf(v + 1e-5f);
    coeffs[c] = sc;
    coeffs[C + c] = b[c] - sc * m * msv;
}

// act: 0 = leaky(0.2), 1 = relu; writes bf16
__global__ __launch_bounds__(256) void k_act(const float* __restrict__ Y, unsigned short* __restrict__ hb,
                                             const float* __restrict__ coeffs, int C, int act) {
    int n = blockIdx.x;
    int c = threadIdx.x;
    if (c >= C) return;
    float v = Y[(size_t)n * 256 + c];
    if (coeffs) v = v * coeffs[c] + coeffs[C + c];
    if (act == 0) v = (v > 0.f) ? v : 0.2f * v;
    else v = fmaxf(v, 0.f);
    hb[(size_t)n * 256 + c] = f2bf(v);
}

// ---------------- pooling (sorted batch -> segmented run reduction) + head ----------------

__global__ __launch_bounds__(128) void k_pool2(const unsigned short* __restrict__ hb, const int* __restrict__ batch,
                                               float* __restrict__ pooled, float* __restrict__ cntg, int N) {
    int t = threadIdx.x;
    int beg = blockIdx.x * 256;
    int end = beg + 256; if (end > N) end = N;
    int cur = batch[beg];
    float acc = 0.f;
    int runlen = 0;
    for (int n = beg; n < end; n++) {
        int b = batch[n];
        if (b != cur) {
            atomicAdd(&pooled[cur * 128 + t], acc);
            if (t == 0) atomicAdd(&cntg[cur], (float)runlen);
            acc = 0.f; runlen = 0; cur = b;
        }
        acc += bf2f(hb[(size_t)n * 256 + t]);
        runlen++;
    }
    atomicAdd(&pooled[cur * 128 + t], acc);
    if (t == 0) atomicAdd(&cntg[cur], (float)runlen);
}

__global__ __launch_bounds__(128) void k_head(const float* __restrict__ pooled, const float* __restrict__ cntg,
                                              const float* __restrict__ W1, const float* __restrict__ b1,
                                              const float* __restrict__ W2, const float* __restrict__ b2,
                                              float* __restrict__ out) {
    __shared__ float p[128];
    __shared__ float h1[64];
    int g = blockIdx.x;
    int t = threadIdx.x;
    float c = cntg[g];
    if (c < 1.f) c = 1.f;
    p[t] = pooled[g * 128 + t] / c;
    __syncthreads();
    if (t < 64) {
        float s = b1[t];
        for (int i = 0; i < 128; i++) s += p[i] * W1[i * 64 + t];
        h1[t] = tanhf(s);
    }
    __syncthreads();
    if (t < 10) {
        float s = b2[t];
        for (int i = 0; i < 64; i++) s += h1[i] * W2[i * 10 + t];
        out[g * 10 + t] = s;
    }
}

// ---------------- orchestration ----------------

extern "C" void kernel_launch(void* const* d_in, const int* in_sizes, int n_in,
                              void* d_out, int out_size, void* d_ws, size_t ws_size,
                              hipStream_t stream) {
    const float* x = (const float*)d_in[0];
    const int* ei = (const int*)d_in[1];
    const int* batch = (const int*)d_in[2];
    const float* convW[6]; const float* convB[6];
    for (int i = 0; i < 6; i++) { convW[i] = (const float*)d_in[3 + 2 * i]; convB[i] = (const float*)d_in[4 + 2 * i]; }
    const float* bnW[4]; const float* bnB[4]; const float* bnMS[4];
    for (int i = 0; i < 4; i++) { bnW[i] = (const float*)d_in[15 + 3 * i]; bnB[i] = (const float*)d_in[16 + 3 * i]; bnMS[i] = (const float*)d_in[17 + 3 * i]; }
    const float* lin1w = (const float*)d_in[27]; const float* lin1b = (const float*)d_in[28];
    const float* lin2w = (const float*)d_in[29]; const float* lin2b = (const float*)d_in[30];
    float* out = (float*)d_out;

    const int N = in_sizes[0] / 128;
    const int E = in_sizes[1] / 2;
    const int G = out_size / 10;

    struct LayerDef { int K, Cin, Cout, bn, ldk; };
    const LayerDef L[6] = {
        {2, 128, 190, 0, 128},
        {2, 190, 256, 1, 192},
        {2, 256, 169, 2, 256},
        {5, 169, 190, -1, 192},
        {1, 190, 256, -1, 192},
        {3, 256, 128, 3, 256},
    };

    char* p = (char*)d_ws;
    auto alloc = [&](size_t bytes) -> void* { void* r = (void*)p; p += (bytes + 255) & ~(size_t)255; return r; };
    float* Yb  = (float*)alloc((size_t)N * 256 * 4);           // GEMM accumulate (fp32)
    float* B1f = (float*)alloc((size_t)N * 256 * 4);           // fp32 tm2 copies (layer 4); head doubles as X0b? no: X0b separate
    float* B2f = (float*)alloc((size_t)N * 256 * 4);
    unsigned short* Hb  = (unsigned short*)alloc((size_t)N * 256 * 2);  // layer input (bf16)
    unsigned short* B1b = (unsigned short*)alloc((size_t)N * 256 * 2);
    unsigned short* B2b = (unsigned short*)alloc((size_t)N * 256 * 2);
    unsigned short* X0b = (unsigned short*)alloc((size_t)N * 256 * 2);
    int2* csr = (int2*)alloc((size_t)E * 8);
    int* row_ptr = (int*)alloc((size_t)(N + 1) * 4);
    int* deg3 = (int*)alloc((size_t)N * 3 * 4);
    int* deg = deg3;
    int* cnt = deg3 + N;
    int* fill = deg3 + 2 * N;
    float* stats = (float*)alloc(512 * 4);
    float* coeffs = (float*)alloc(512 * 4);
    float* pooled = (float*)alloc((size_t)G * 128 * 4);
    float* cntg = (float*)alloc((size_t)G * 4);
    unsigned short* WT[6];
    for (int i = 0; i < 6; i++) WT[i] = (unsigned short*)alloc((size_t)L[i].K * L[i].Cout * L[i].ldk * 2);

    hipMemsetAsync(deg3, 0, (size_t)N * 3 * 4, stream);
    k_deg_hist<<<cdiv(E, 256), 256, 0, stream>>>(ei, E, deg, cnt);
    k_scan<<<1, 1024, 0, stream>>>(cnt, row_ptr, N, E);
    k_scatter<<<cdiv(E, 256), 256, 0, stream>>>(ei, E, deg, row_ptr, fill, csr);
    for (int i = 0; i < 6; i++) {
        int total = L[i].K * L[i].Cout * L[i].ldk;
        k_wconv<<<cdiv(total, 256), 256, 0, stream>>>(convW[i], WT[i], L[i].Cin, L[i].Cout, L[i].ldk, total);
    }
    k_x0<<<N, 128, 0, stream>>>(x, X0b, N);

    const unsigned short* hin = X0b;
    for (int li = 0; li < 6; li++) {
        const int K = L[li].K, Cin = L[li].Cin, Cout = L[li].Cout, ldk = L[li].ldk;
        const int C4 = (Cin + 3) / 4;
        dim3 gg(cdiv(Cout, 64), cdiv(N, 256));
        // term 0
        k_gemm_mfma<<<gg, 256, 0, stream>>>(hin, WT[li], ldk, convB[li], Yb, N, Cin, Cout, 0);
        if (K > 1) {
            // T1 = prop(T0); keep fp32 copy only for layer 4 (used as tm2 at k=3)
            float* t1f = (li == 3) ? B1f : nullptr;
            k_prop_bf<<<cdiv(N, 4), 256, 0, stream>>>(hin, B1b, t1f, nullptr, nullptr, row_ptr, csr, C4, N);
            k_gemm_mfma<<<gg, 256, 0, stream>>>(B1b, WT[li] + (size_t)Cout * ldk, ldk, nullptr, Yb, N, Cin, Cout, 1);
            if (K > 2) {
                // T2 = 2*prop(T1) - T0 (tm2 = layer input, bf16)
                float* t2f = (li == 3) ? B2f : nullptr;
                k_prop_bf<<<cdiv(N, 4), 256, 0, stream>>>(B1b, B2b, t2f, hin, nullptr, row_ptr, csr, C4, N);
                k_gemm_mfma<<<gg, 256, 0, stream>>>(B2b, WT[li] + (size_t)2 * Cout * ldk, ldk, nullptr, Yb, N, Cin, Cout, 1);
                // k>=3: T_k = 2*prop(T_{k-1}) - T_{k-2}; overwrite T_{k-2}'s bf16 buffer, fp32 tm2
                const unsigned short* tin = B2b;
                unsigned short* toutb = B1b;
                const float* tmf = B1f;
                for (int k = 3; k < K; k++) {
                    k_prop_bf<<<cdiv(N, 4), 256, 0, stream>>>(tin, toutb, nullptr, nullptr, tmf, row_ptr, csr, C4, N);
                    k_gemm_mfma<<<gg, 256, 0, stream>>>(toutb, WT[li] + (size_t)k * Cout * ldk, ldk, nullptr, Yb, N, Cin, Cout, 1);
                    // rotate: next reads toutb, overwrites the other buffer
                    const unsigned short* nt = toutb;
                    toutb = (unsigned short*)tin;
                    tin = nt;
                    tmf = (tmf == B1f) ? B2f : B1f;
                }
            }
        }
        // norm + act -> Hb
        if (L[li].bn >= 0) {
            hipMemsetAsync(stats, 0, 512 * 4, stream);
            k_stats<<<256, 256, 0, stream>>>(Yb, stats, N, Cout);
            k_coeffs<<<1, 256, 0, stream>>>(stats, bnW[L[li].bn], bnB[L[li].bn], bnMS[L[li].bn], coeffs, N, Cout);
            k_act<<<N, 256, 0, stream>>>(Yb, Hb, coeffs, Cout, 0);
        } else {
            k_act<<<N, 256, 0, stream>>>(Yb, Hb, nullptr, Cout, 1);
        }
        hin = Hb;
    }

    hipMemsetAsync(pooled, 0, (size_t)G * 128 * 4, stream);
    hipMemsetAsync(cntg, 0, (size_t)G * 4, stream);
    k_pool2<<<cdiv(N, 256), 128, 0, stream>>>(Hb, batch, pooled, cntg, N);
    k_head<<<G, 128, 0, stream>>>(pooled, cntg, lin1w, lin1b, lin2w, lin2b, out);
}

// Round 5
// 1188.134 us; speedup vs baseline: 2.6909x; 1.2522x over previous
//
#include <hip/hip_runtime.h>
#include <math.h>

static inline int cdiv(int a, int b) { return (a + b - 1) / b; }

typedef __attribute__((ext_vector_type(8))) short short8;
typedef __attribute__((ext_vector_type(4))) float floatx4;

__device__ inline unsigned short f2bf(float f) {
    unsigned int u = __float_as_uint(f);
    unsigned int r = (u + 0x7fffu + ((u >> 16) & 1u)) >> 16;
    return (unsigned short)r;
}
__device__ inline float bf2f(unsigned short u) {
    return __uint_as_float(((unsigned int)u) << 16);
}

// ---------------- CSR build ----------------

__global__ __launch_bounds__(256) void k_deg_hist(const int* __restrict__ ei, int E,
                                                  int* __restrict__ deg, int* __restrict__ cnt) {
    int e = blockIdx.x * 256 + threadIdx.x;
    if (e >= E) return;
    int s = ei[e], d = ei[E + e];
    if (s != d) atomicAdd(&deg[s], 1);
    atomicAdd(&cnt[d], 1);
}

__global__ __launch_bounds__(1024) void k_scan(const int* __restrict__ cnt, int* __restrict__ row_ptr,
                                               int N, int E) {
    __shared__ int part[1024];
    int t = threadIdx.x;
    int chunk = (N + 1023) / 1024;
    int beg = t * chunk;
    int end = beg + chunk; if (end > N) end = N;
    int s = 0;
    for (int i = beg; i < end; i++) s += cnt[i];
    part[t] = s;
    __syncthreads();
    for (int off = 1; off < 1024; off <<= 1) {
        int v = (t >= off) ? part[t - off] : 0;
        __syncthreads();
        part[t] += v;
        __syncthreads();
    }
    int base = (t > 0) ? part[t - 1] : 0;
    for (int i = beg; i < end; i++) { row_ptr[i] = base; base += cnt[i]; }
    if (t == 1023) row_ptr[N] = E;
}

__global__ __launch_bounds__(256) void k_scatter(const int* __restrict__ ei, int E,
                                                 const int* __restrict__ deg,
                                                 const int* __restrict__ row_ptr,
                                                 int* __restrict__ fill, int2* __restrict__ csr) {
    int e = blockIdx.x * 256 + threadIdx.x;
    if (e >= E) return;
    int s = ei[e], d = ei[E + e];
    float v = 0.f;
    if (s != d) {
        int a = deg[s], b = deg[d];
        float fa = (a > 0) ? 1.f / sqrtf((float)a) : 0.f;
        float fb = (b > 0) ? 1.f / sqrtf((float)b) : 0.f;
        v = -fa * fb;
    }
    int pos = row_ptr[d] + atomicAdd(&fill[d], 1);
    if (pos < E) csr[pos] = make_int2(s, __float_as_int(v));
}

// -------- weight convert: W[K][Cin][Cout] fp32 -> WT[Cout][K*256] bf16 (term-blocked, k zero-padded) ---

__global__ __launch_bounds__(256) void k_wconv(const float* __restrict__ W, unsigned short* __restrict__ WT,
                                               int Cin, int Cout, int ldk, int total) {
    int idx = blockIdx.x * 256 + threadIdx.x;
    if (idx >= total) return;
    int n = idx / ldk;
    int rem = idx - n * ldk;
    int term = rem >> 8;
    int k = rem & 255;
    float v = (k < Cin) ? W[(size_t)term * Cin * Cout + (size_t)k * Cout + n] : 0.f;
    WT[idx] = f2bf(v);
}

// ---------------- x (fp32, ld 128) -> wide bf16, stride 512, cols 0..127 ----------------

__global__ __launch_bounds__(128) void k_x0(const float* __restrict__ x, unsigned short* __restrict__ xb, int N) {
    int n = blockIdx.x;
    int c = threadIdx.x;
    xb[(size_t)n * 512 + c] = f2bf(x[(size_t)n * 128 + c]);
}

// ---------------- propagation (bf16 gather, fp32 accumulate) ----------------
// out[n][c] = sum_e norm_e * in[src_e][c]; if tm2*: r = 2*acc - tm2.
// in/outb/tm2b share row stride ld4 (in ushort4 units). outf/tm2f fp32 at fixed stride 48 float4s.

__global__ __launch_bounds__(256) void k_prop_bf(const unsigned short* __restrict__ in,
                                                 unsigned short* __restrict__ outb,
                                                 float* __restrict__ outf,
                                                 const unsigned short* __restrict__ tm2b,
                                                 const float* __restrict__ tm2f,
                                                 const int* __restrict__ row_ptr,
                                                 const int2* __restrict__ csr, int C4, int Nn, int ld4) {
    int node = (blockIdx.x << 2) + (threadIdx.x >> 6);
    if (node >= Nn) return;
    int lane = threadIdx.x & 63;
    if (lane >= C4) return;
    int beg = row_ptr[node], end = row_ptr[node + 1];
    const ushort4* h4 = (const ushort4*)in;
    float a0 = 0.f, a1 = 0.f, a2 = 0.f, a3 = 0.f;
    int j = beg;
    for (; j + 2 <= end; j += 2) {
        int2 e0 = csr[j];
        int2 e1 = csr[j + 1];
        ushort4 v0 = h4[(size_t)e0.x * ld4 + lane];
        ushort4 v1 = h4[(size_t)e1.x * ld4 + lane];
        float n0 = __int_as_float(e0.y), n1 = __int_as_float(e1.y);
        a0 += n0 * bf2f(v0.x) + n1 * bf2f(v1.x);
        a1 += n0 * bf2f(v0.y) + n1 * bf2f(v1.y);
        a2 += n0 * bf2f(v0.z) + n1 * bf2f(v1.z);
        a3 += n0 * bf2f(v0.w) + n1 * bf2f(v1.w);
    }
    if (j < end) {
        int2 e0 = csr[j];
        ushort4 v0 = h4[(size_t)e0.x * ld4 + lane];
        float n0 = __int_as_float(e0.y);
        a0 += n0 * bf2f(v0.x); a1 += n0 * bf2f(v0.y); a2 += n0 * bf2f(v0.z); a3 += n0 * bf2f(v0.w);
    }
    if (tm2b) {
        ushort4 t = ((const ushort4*)tm2b)[(size_t)node * ld4 + lane];
        a0 = 2.f * a0 - bf2f(t.x); a1 = 2.f * a1 - bf2f(t.y);
        a2 = 2.f * a2 - bf2f(t.z); a3 = 2.f * a3 - bf2f(t.w);
    } else if (tm2f) {
        float4 t = ((const float4*)tm2f)[(size_t)node * 48 + lane];
        a0 = 2.f * a0 - t.x; a1 = 2.f * a1 - t.y; a2 = 2.f * a2 - t.z; a3 = 2.f * a3 - t.w;
    }
    ushort4 r;
    r.x = f2bf(a0); r.y = f2bf(a1); r.z = f2bf(a2); r.w = f2bf(a3);
    ((ushort4*)outb)[(size_t)node * ld4 + lane] = r;
    if (outf) ((float4*)outf)[(size_t)node * 48 + lane] = make_float4(a0, a1, a2, a3);
}

// ------- wide bf16 MFMA GEMM: Y = A(bf16, lda) @ WT^T + bias; optional fused col-stats -------
// BM=BN=128, BK=32; 4 waves in 2x2; each wave 64x64 as 4x4 frags of 16x16x32.

__global__ __launch_bounds__(256, 2) void k_gemm_w(const unsigned short* __restrict__ A, int lda,
                                                   const unsigned short* __restrict__ WT,
                                                   const float* __restrict__ bias,
                                                   float* __restrict__ Y,
                                                   float* __restrict__ stats,
                                                   int M, int Kp, int Cout) {
    __shared__ unsigned short As[128][40];
    __shared__ unsigned short Bs[128][40];
    const int t = threadIdx.x;
    const int bm = blockIdx.y * 128, bn = blockIdx.x * 128;
    const int w = t >> 6, lane = t & 63;
    const int wr = w >> 1, wc = w & 1;
    const int fr = lane & 15, fg = lane >> 4;
    const int srow = t >> 2;        // 0..63
    const int skq = (t & 3) * 8;    // 0,8,16,24

    floatx4 acc[4][4];
#pragma unroll
    for (int i = 0; i < 4; i++)
#pragma unroll
        for (int j = 0; j < 4; j++) acc[i][j] = (floatx4){0.f, 0.f, 0.f, 0.f};

    for (int k0 = 0; k0 < Kp; k0 += 32) {
#pragma unroll
        for (int p = 0; p < 2; p++) {
            int r = p * 64 + srow;
            int grow = bm + r;
            uint4 av = make_uint4(0u, 0u, 0u, 0u);
            if (grow < M) av = *(const uint4*)&A[(size_t)grow * lda + k0 + skq];
            *(uint4*)&As[r][skq] = av;
            int gn = bn + r;
            uint4 bv = make_uint4(0u, 0u, 0u, 0u);
            if (gn < Cout) bv = *(const uint4*)&WT[(size_t)gn * lda + k0 + skq];
            *(uint4*)&Bs[r][skq] = bv;
        }
        __syncthreads();

        short8 a[4], b[4];
#pragma unroll
        for (int i = 0; i < 4; i++) a[i] = *(const short8*)&As[64 * wr + 16 * i + fr][fg * 8];
#pragma unroll
        for (int j = 0; j < 4; j++) b[j] = *(const short8*)&Bs[64 * wc + 16 * j + fr][fg * 8];
#pragma unroll
        for (int i = 0; i < 4; i++)
#pragma unroll
            for (int j = 0; j < 4; j++)
                acc[i][j] = __builtin_amdgcn_mfma_f32_16x16x32_bf16(a[i], b[j], acc[i][j], 0, 0, 0);
        __syncthreads();
    }

    // epilogue: C/D layout col=lane&15, row=(lane>>4)*4+q
    float s1[4] = {0.f, 0.f, 0.f, 0.f};
    float s2[4] = {0.f, 0.f, 0.f, 0.f};
#pragma unroll
    for (int j = 0; j < 4; j++) {
        int c = bn + 64 * wc + 16 * j + fr;
#pragma unroll
        for (int i = 0; i < 4; i++) {
#pragma unroll
            for (int q = 0; q < 4; q++) {
                int r = bm + 64 * wr + 16 * i + fg * 4 + q;
                float v = 0.f;
                if (r < M && c < Cout) {
                    v = acc[i][j][q] + bias[c];
                    Y[(size_t)r * 256 + c] = v;
                }
                s1[j] += v;
                s2[j] += v * v;
            }
        }
    }
    if (stats) {
#pragma unroll
        for (int j = 0; j < 4; j++) {
            s1[j] += __shfl_xor(s1[j], 16, 64);
            s1[j] += __shfl_xor(s1[j], 32, 64);
            s2[j] += __shfl_xor(s2[j], 16, 64);
            s2[j] += __shfl_xor(s2[j], 32, 64);
            if (fg == 0) {
                int c = bn + 64 * wc + 16 * j + fr;
                if (c < Cout) {
                    atomicAdd(&stats[c], s1[j]);
                    atomicAdd(&stats[256 + c], s2[j]);
                }
            }
        }
    }
}

// ---------------- GraphNorm coeffs ----------------

__global__ __launch_bounds__(256) void k_coeffs(const float* __restrict__ stats,
                                                const float* __restrict__ w, const float* __restrict__ b,
                                                const float* __restrict__ ms,
                                                float* __restrict__ coeffs, int N, int C) {
    int c = threadIdx.x;
    if (c >= C) return;
    float m = stats[c] / (float)N;
    float q = stats[256 + c] / (float)N;
    float msv = ms[c];
    float v = q - m * m * msv * (2.f - msv);
    float sc = w[c] / sqrtf(v + 1e-5f);
    coeffs[c] = sc;
    coeffs[256 + c] = b[c] - sc * m * msv;
}

// act: 0 = leaky(0.2), 1 = relu; reads Yb (fp32, stride 256), writes bf16 at out stride
__global__ __launch_bounds__(256) void k_act(const float* __restrict__ Y, unsigned short* __restrict__ hb,
                                             int ldo, const float* __restrict__ coeffs, int C, int act) {
    int n = blockIdx.x;
    int c = threadIdx.x;
    if (c >= C) return;
    float v = Y[(size_t)n * 256 + c];
    if (coeffs) v = v * coeffs[c] + coeffs[256 + c];
    if (act == 0) v = (v > 0.f) ? v : 0.2f * v;
    else v = fmaxf(v, 0.f);
    hb[(size_t)n * ldo + c] = f2bf(v);
}

// ---------------- pooling (sorted batch -> segmented run reduction) + head ----------------

__global__ __launch_bounds__(128) void k_pool2(const unsigned short* __restrict__ hb, const int* __restrict__ batch,
                                               float* __restrict__ pooled, float* __restrict__ cntg, int N) {
    int t = threadIdx.x;
    int beg = blockIdx.x * 256;
    int end = beg + 256; if (end > N) end = N;
    int cur = batch[beg];
    float acc = 0.f;
    int runlen = 0;
    for (int n = beg; n < end; n++) {
        int b = batch[n];
        if (b != cur) {
            atomicAdd(&pooled[cur * 128 + t], acc);
            if (t == 0) atomicAdd(&cntg[cur], (float)runlen);
            acc = 0.f; runlen = 0; cur = b;
        }
        acc += bf2f(hb[(size_t)n * 256 + t]);
        runlen++;
    }
    atomicAdd(&pooled[cur * 128 + t], acc);
    if (t == 0) atomicAdd(&cntg[cur], (float)runlen);
}

__global__ __launch_bounds__(128) void k_head(const float* __restrict__ pooled, const float* __restrict__ cntg,
                                              const float* __restrict__ W1, const float* __restrict__ b1,
                                              const float* __restrict__ W2, const float* __restrict__ b2,
                                              float* __restrict__ out) {
    __shared__ float p[128];
    __shared__ float h1[64];
    int g = blockIdx.x;
    int t = threadIdx.x;
    float c = cntg[g];
    if (c < 1.f) c = 1.f;
    p[t] = pooled[g * 128 + t] / c;
    __syncthreads();
    if (t < 64) {
        float s = b1[t];
        for (int i = 0; i < 128; i++) s += p[i] * W1[i * 64 + t];
        h1[t] = tanhf(s);
    }
    __syncthreads();
    if (t < 10) {
        float s = b2[t];
        for (int i = 0; i < 64; i++) s += h1[i] * W2[i * 10 + t];
        out[g * 10 + t] = s;
    }
}

// ---------------- orchestration ----------------

extern "C" void kernel_launch(void* const* d_in, const int* in_sizes, int n_in,
                              void* d_out, int out_size, void* d_ws, size_t ws_size,
                              hipStream_t stream) {
    const float* x = (const float*)d_in[0];
    const int* ei = (const int*)d_in[1];
    const int* batch = (const int*)d_in[2];
    const float* convW[6]; const float* convB[6];
    for (int i = 0; i < 6; i++) { convW[i] = (const float*)d_in[3 + 2 * i]; convB[i] = (const float*)d_in[4 + 2 * i]; }
    const float* bnW[4]; const float* bnB[4]; const float* bnMS[4];
    for (int i = 0; i < 4; i++) { bnW[i] = (const float*)d_in[15 + 3 * i]; bnB[i] = (const float*)d_in[16 + 3 * i]; bnMS[i] = (const float*)d_in[17 + 3 * i]; }
    const float* lin1w = (const float*)d_in[27]; const float* lin1b = (const float*)d_in[28];
    const float* lin2w = (const float*)d_in[29]; const float* lin2b = (const float*)d_in[30];
    float* out = (float*)d_out;

    const int N = in_sizes[0] / 128;
    const int E = in_sizes[1] / 2;
    const int G = out_size / 10;

    struct LayerDef { int K, Cin, Cout, bn; };
    const LayerDef L[6] = {
        {2, 128, 190, 0},
        {2, 190, 256, 1},
        {2, 256, 169, 2},
        {5, 169, 190, -1},
        {1, 190, 256, -1},
        {3, 256, 128, 3},
    };
    const int stride[6] = {512, 512, 512, 1280, 256, 768};

    char* p = (char*)d_ws;
    auto alloc = [&](size_t bytes) -> void* { void* r = (void*)p; p += (bytes + 255) & ~(size_t)255; return r; };
    unsigned short* wide = (unsigned short*)alloc((size_t)N * 1280 * 2);  // all Chebyshev terms, bf16
    float* Yb  = (float*)alloc((size_t)N * 256 * 4);                      // GEMM output (fp32)
    float* B1f = (float*)alloc((size_t)N * 192 * 4);                      // fp32 tm2 copies (layer 4)
    float* B2f = (float*)alloc((size_t)N * 192 * 4);
    int2* csr = (int2*)alloc((size_t)E * 8);
    int* row_ptr = (int*)alloc((size_t)(N + 1) * 4);
    int* deg3 = (int*)alloc((size_t)N * 3 * 4);
    int* deg = deg3;
    int* cnt = deg3 + N;
    int* fill = deg3 + 2 * N;
    float* stats = (float*)alloc(512 * 4);
    float* coeffs = (float*)alloc(512 * 4);
    float* pooled = (float*)alloc((size_t)G * 129 * 4);
    float* cntg = pooled + (size_t)G * 128;
    unsigned short* WT[6];
    for (int i = 0; i < 6; i++) WT[i] = (unsigned short*)alloc((size_t)L[i].Cout * L[i].K * 256 * 2);

    hipMemsetAsync(deg3, 0, (size_t)N * 3 * 4, stream);
    k_deg_hist<<<cdiv(E, 256), 256, 0, stream>>>(ei, E, deg, cnt);
    k_scan<<<1, 1024, 0, stream>>>(cnt, row_ptr, N, E);
    k_scatter<<<cdiv(E, 256), 256, 0, stream>>>(ei, E, deg, row_ptr, fill, csr);
    for (int i = 0; i < 6; i++) {
        int ldk = L[i].K * 256;
        int total = L[i].Cout * ldk;
        k_wconv<<<cdiv(total, 256), 256, 0, stream>>>(convW[i], WT[i], L[i].Cin, L[i].Cout, ldk, total);
    }
    k_x0<<<N, 128, 0, stream>>>(x, wide, N);

    for (int li = 0; li < 6; li++) {
        const int K = L[li].K, Cin = L[li].Cin, Cout = L[li].Cout;
        const int st = stride[li], ld4 = st / 4;
        const int C4 = (Cin + 3) / 4;
        const int pgrid = cdiv(N, 4);

        if (K >= 2)  // T1 = prop(T0)
            k_prop_bf<<<pgrid, 256, 0, stream>>>(wide, wide + 256, (li == 3) ? B1f : nullptr,
                                                 nullptr, nullptr, row_ptr, csr, C4, N, ld4);
        if (K >= 3)  // T2 = 2*prop(T1) - T0
            k_prop_bf<<<pgrid, 256, 0, stream>>>(wide + 256, wide + 512, (li == 3) ? B2f : nullptr,
                                                 wide, nullptr, row_ptr, csr, C4, N, ld4);
        if (li == 3) {
            // T3 = 2*prop(T2) - T1 (fp32 tm2 = B1f; overwrite B1f with T3 fp32)
            k_prop_bf<<<pgrid, 256, 0, stream>>>(wide + 512, wide + 768, B1f,
                                                 nullptr, B1f, row_ptr, csr, C4, N, ld4);
            // T4 = 2*prop(T3) - T2 (fp32 tm2 = B2f)
            k_prop_bf<<<pgrid, 256, 0, stream>>>(wide + 768, wide + 1024, nullptr,
                                                 nullptr, B2f, row_ptr, csr, C4, N, ld4);
        }

        const int bnidx = L[li].bn;
        if (bnidx >= 0) hipMemsetAsync(stats, 0, 512 * 4, stream);
        dim3 gg(cdiv(Cout, 128), cdiv(N, 128));
        k_gemm_w<<<gg, 256, 0, stream>>>(wide, st, WT[li], convB[li], Yb,
                                         (bnidx >= 0) ? stats : nullptr, N, st, Cout);
        const int nxt = (li < 5) ? stride[li + 1] : 256;
        if (bnidx >= 0) {
            k_coeffs<<<1, 256, 0, stream>>>(stats, bnW[bnidx], bnB[bnidx], bnMS[bnidx], coeffs, N, Cout);
            k_act<<<N, 256, 0, stream>>>(Yb, wide, nxt, coeffs, Cout, 0);
        } else {
            k_act<<<N, 256, 0, stream>>>(Yb, wide, nxt, nullptr, Cout, 1);
        }
    }

    hipMemsetAsync(pooled, 0, (size_t)G * 129 * 4, stream);
    k_pool2<<<cdiv(N, 256), 128, 0, stream>>>(wide, batch, pooled, cntg, N);
    k_head<<<G, 128, 0, stream>>>(pooled, cntg, lin1w, lin1b, lin2w, lin2b, out);
}

// Round 7
// 1157.880 us; speedup vs baseline: 2.7612x; 1.0261x over previous
//
#include <hip/hip_runtime.h>
#include <math.h>

static inline int cdiv(int a, int b) { return (a + b - 1) / b; }

typedef __attribute__((ext_vector_type(8))) short short8;
typedef __attribute__((ext_vector_type(4))) float floatx4;

__device__ inline unsigned short f2bf(float f) {
    unsigned int u = __float_as_uint(f);
    unsigned int r = (u + 0x7fffu + ((u >> 16) & 1u)) >> 16;
    return (unsigned short)r;
}
__device__ inline float bf2f(unsigned short u) {
    return __uint_as_float(((unsigned int)u) << 16);
}

// ---------------- CSR build ----------------

__global__ __launch_bounds__(256) void k_deg_hist(const int* __restrict__ ei, int E,
                                                  int* __restrict__ deg, int* __restrict__ cnt) {
    int e = blockIdx.x * 256 + threadIdx.x;
    if (e >= E) return;
    int s = ei[e], d = ei[E + e];
    if (s != d) atomicAdd(&deg[s], 1);
    atomicAdd(&cnt[d], 1);
}

__global__ __launch_bounds__(1024) void k_scan(const int* __restrict__ cnt, int* __restrict__ row_ptr,
                                               int N, int E) {
    __shared__ int part[1024];
    int t = threadIdx.x;
    int chunk = (N + 1023) / 1024;
    int beg = t * chunk;
    int end = beg + chunk; if (end > N) end = N;
    int s = 0;
    for (int i = beg; i < end; i++) s += cnt[i];
    part[t] = s;
    __syncthreads();
    for (int off = 1; off < 1024; off <<= 1) {
        int v = (t >= off) ? part[t - off] : 0;
        __syncthreads();
        part[t] += v;
        __syncthreads();
    }
    int base = (t > 0) ? part[t - 1] : 0;
    for (int i = beg; i < end; i++) { row_ptr[i] = base; base += cnt[i]; }
    if (t == 1023) row_ptr[N] = E;
}

__global__ __launch_bounds__(256) void k_scatter(const int* __restrict__ ei, int E,
                                                 const int* __restrict__ deg,
                                                 const int* __restrict__ row_ptr,
                                                 int* __restrict__ fill, int2* __restrict__ csr) {
    int e = blockIdx.x * 256 + threadIdx.x;
    if (e >= E) return;
    int s = ei[e], d = ei[E + e];
    float v = 0.f;
    if (s != d) {
        int a = deg[s], b = deg[d];
        float fa = (a > 0) ? 1.f / sqrtf((float)a) : 0.f;
        float fb = (b > 0) ? 1.f / sqrtf((float)b) : 0.f;
        v = -fa * fb;
    }
    int pos = row_ptr[d] + atomicAdd(&fill[d], 1);
    if (pos < E) csr[pos] = make_int2(s, __float_as_int(v));
}

// -------- weight convert: W[K][Cin][Cout] fp32 -> WT[Cout][K*256] bf16 (term-blocked, k zero-padded) ---

__global__ __launch_bounds__(256) void k_wconv(const float* __restrict__ W, unsigned short* __restrict__ WT,
                                               int Cin, int Cout, int ldk, int total) {
    int idx = blockIdx.x * 256 + threadIdx.x;
    if (idx >= total) return;
    int n = idx / ldk;
    int rem = idx - n * ldk;
    int term = rem >> 8;
    int k = rem & 255;
    float v = (k < Cin) ? W[(size_t)term * Cin * Cout + (size_t)k * Cout + n] : 0.f;
    WT[idx] = f2bf(v);
}

// ---------------- x (fp32, ld 128) -> wide bf16, stride 512, cols 0..127 ----------------

__global__ __launch_bounds__(128) void k_x0(const float* __restrict__ x, unsigned short* __restrict__ xb, int N) {
    int n = blockIdx.x;
    int c = threadIdx.x;
    xb[(size_t)n * 512 + c] = f2bf(x[(size_t)n * 128 + c]);
}

// ---------------- chunked propagation (bf16 gather, fp32 accumulate) ----------------
// Channel chunk = 16 ushort4 lanes = 64 channels = 128B per edge-row (one cacheline).
// Chunk is pinned to XCDs via slot = blockIdx.x & 7 so each XCD's L2 holds only its
// 30000 x 128B = 3.84 MB slice (< 4 MiB). Edge order per node unchanged -> bitwise-identical.
// out[n][c] = sum_e norm_e * in[src_e][c]; if tm2*: r = 2*acc - tm2.
// in/outb/tm2b row stride ld4 (ushort4 units). outf/tm2f fp32 at stride 48 float4.

#define PNB 16  // nodes per block (16 groups of 16 lanes)

__global__ __launch_bounds__(256) void k_prop_c(const unsigned short* __restrict__ in,
                                                unsigned short* __restrict__ outb,
                                                float* __restrict__ outf,
                                                const unsigned short* __restrict__ tm2b,
                                                const float* __restrict__ tm2f,
                                                const int* __restrict__ row_ptr,
                                                const int2* __restrict__ csr,
                                                int C4, int nch, int Nn, int ld4) {
    const int slot = blockIdx.x & 7;
    const int chunk = (slot * nch) >> 3;
    const int first = (chunk * 8 + nch - 1) / nch;
    const int next  = ((chunk + 1) * 8 + nch - 1) / nch;
    const int rank = slot - first, m = next - first;
    const int NB = (Nn + PNB - 1) / PNB;
    const int bi = (int)(blockIdx.x >> 3) * m + rank;
    if (bi >= NB) return;
    const int group = threadIdx.x >> 4;
    const int glane = threadIdx.x & 15;
    const int node = bi * PNB + group;
    if (node >= Nn) return;
    const int lane4 = chunk * 16 + glane;
    if (lane4 >= C4) return;

    int beg = row_ptr[node], end = row_ptr[node + 1];
    const ushort4* h4 = (const ushort4*)in;
    float a0 = 0.f, a1 = 0.f, a2 = 0.f, a3 = 0.f;
    int j = beg;
    for (; j + 2 <= end; j += 2) {
        int2 e0 = csr[j];
        int2 e1 = csr[j + 1];
        ushort4 v0 = h4[(size_t)e0.x * ld4 + lane4];
        ushort4 v1 = h4[(size_t)e1.x * ld4 + lane4];
        float n0 = __int_as_float(e0.y), n1 = __int_as_float(e1.y);
        a0 += n0 * bf2f(v0.x) + n1 * bf2f(v1.x);
        a1 += n0 * bf2f(v0.y) + n1 * bf2f(v1.y);
        a2 += n0 * bf2f(v0.z) + n1 * bf2f(v1.z);
        a3 += n0 * bf2f(v0.w) + n1 * bf2f(v1.w);
    }
    if (j < end) {
        int2 e0 = csr[j];
        ushort4 v0 = h4[(size_t)e0.x * ld4 + lane4];
        float n0 = __int_as_float(e0.y);
        a0 += n0 * bf2f(v0.x); a1 += n0 * bf2f(v0.y); a2 += n0 * bf2f(v0.z); a3 += n0 * bf2f(v0.w);
    }
    if (tm2b) {
        ushort4 t = ((const ushort4*)tm2b)[(size_t)node * ld4 + lane4];
        a0 = 2.f * a0 - bf2f(t.x); a1 = 2.f * a1 - bf2f(t.y);
        a2 = 2.f * a2 - bf2f(t.z); a3 = 2.f * a3 - bf2f(t.w);
    } else if (tm2f) {
        float4 t = ((const float4*)tm2f)[(size_t)node * 48 + lane4];
        a0 = 2.f * a0 - t.x; a1 = 2.f * a1 - t.y; a2 = 2.f * a2 - t.z; a3 = 2.f * a3 - t.w;
    }
    ushort4 r;
    r.x = f2bf(a0); r.y = f2bf(a1); r.z = f2bf(a2); r.w = f2bf(a3);
    ((ushort4*)outb)[(size_t)node * ld4 + lane4] = r;
    if (outf) ((float4*)outf)[(size_t)node * 48 + lane4] = make_float4(a0, a1, a2, a3);
}

// ------- wide bf16 MFMA GEMM: A(bf16, lda) @ WT^T + bias -------
// If stats != null: write Y fp32 (stride 256) + fused column sum/sumsq.
// Else: fused ReLU, write bf16 to hb at stride ldo; cols in [Cout, tile-edge) are
// ZERO-FILLED so a downstream GEMM reading the padded K-region sees exact zeros
// (never reinterpreted-fp32 garbage, which can decode as bf16 NaN and poison
// 0-weight MFMA products: 0*NaN=NaN, then fmaxf(NaN,0)=0 silently corrupts).
// BM=BN=128, BK=32; 4 waves in 2x2; each wave 64x64 as 4x4 frags of 16x16x32.

__global__ __launch_bounds__(256, 2) void k_gemm_w(const unsigned short* __restrict__ A, int lda,
                                                   const unsigned short* __restrict__ WT,
                                                   const float* __restrict__ bias,
                                                   float* __restrict__ Y,
                                                   float* __restrict__ stats,
                                                   unsigned short* __restrict__ hb, int ldo,
                                                   int M, int Kp, int Cout) {
    __shared__ unsigned short As[128][40];
    __shared__ unsigned short Bs[128][40];
    const int t = threadIdx.x;
    const int bm = blockIdx.y * 128, bn = blockIdx.x * 128;
    const int w = t >> 6, lane = t & 63;
    const int wr = w >> 1, wc = w & 1;
    const int fr = lane & 15, fg = lane >> 4;
    const int srow = t >> 2;
    const int skq = (t & 3) * 8;

    floatx4 acc[4][4];
#pragma unroll
    for (int i = 0; i < 4; i++)
#pragma unroll
        for (int j = 0; j < 4; j++) acc[i][j] = (floatx4){0.f, 0.f, 0.f, 0.f};

    for (int k0 = 0; k0 < Kp; k0 += 32) {
#pragma unroll
        for (int p = 0; p < 2; p++) {
            int r = p * 64 + srow;
            int grow = bm + r;
            uint4 av = make_uint4(0u, 0u, 0u, 0u);
            if (grow < M) av = *(const uint4*)&A[(size_t)grow * lda + k0 + skq];
            *(uint4*)&As[r][skq] = av;
            int gn = bn + r;
            uint4 bv = make_uint4(0u, 0u, 0u, 0u);
            if (gn < Cout) bv = *(const uint4*)&WT[(size_t)gn * lda + k0 + skq];
            *(uint4*)&Bs[r][skq] = bv;
        }
        __syncthreads();

        short8 a[4], b[4];
#pragma unroll
        for (int i = 0; i < 4; i++) a[i] = *(const short8*)&As[64 * wr + 16 * i + fr][fg * 8];
#pragma unroll
        for (int j = 0; j < 4; j++) b[j] = *(const short8*)&Bs[64 * wc + 16 * j + fr][fg * 8];
#pragma unroll
        for (int i = 0; i < 4; i++)
#pragma unroll
            for (int j = 0; j < 4; j++)
                acc[i][j] = __builtin_amdgcn_mfma_f32_16x16x32_bf16(a[i], b[j], acc[i][j], 0, 0, 0);
        __syncthreads();
    }

    // epilogue: C/D layout col=lane&15, row=(lane>>4)*4+q
    if (stats) {
        float s1[4] = {0.f, 0.f, 0.f, 0.f};
        float s2[4] = {0.f, 0.f, 0.f, 0.f};
#pragma unroll
        for (int j = 0; j < 4; j++) {
            int c = bn + 64 * wc + 16 * j + fr;
#pragma unroll
            for (int i = 0; i < 4; i++) {
#pragma unroll
                for (int q = 0; q < 4; q++) {
                    int r = bm + 64 * wr + 16 * i + fg * 4 + q;
                    float v = 0.f;
                    if (r < M && c < Cout) {
                        v = acc[i][j][q] + bias[c];
                        Y[(size_t)r * 256 + c] = v;
                    }
                    s1[j] += v;
                    s2[j] += v * v;
                }
            }
        }
#pragma unroll
        for (int j = 0; j < 4; j++) {
            s1[j] += __shfl_xor(s1[j], 16, 64);
            s1[j] += __shfl_xor(s1[j], 32, 64);
            s2[j] += __shfl_xor(s2[j], 16, 64);
            s2[j] += __shfl_xor(s2[j], 32, 64);
            if (fg == 0) {
                int c = bn + 64 * wc + 16 * j + fr;
                if (c < Cout) {
                    atomicAdd(&stats[c], s1[j]);
                    atomicAdd(&stats[256 + c], s2[j]);
                }
            }
        }
    } else {
        // fused ReLU -> bf16; zero-fill padding cols [Cout, tile-edge)
#pragma unroll
        for (int j = 0; j < 4; j++) {
            int c = bn + 64 * wc + 16 * j + fr;
            float bc = (c < Cout) ? bias[c] : 0.f;
#pragma unroll
            for (int i = 0; i < 4; i++) {
#pragma unroll
                for (int q = 0; q < 4; q++) {
                    int r = bm + 64 * wr + 16 * i + fg * 4 + q;
                    if (r < M) {
                        float v = (c < Cout) ? fmaxf(acc[i][j][q] + bc, 0.f) : 0.f;
                        hb[(size_t)r * ldo + c] = f2bf(v);
                    }
                }
            }
        }
    }
}

// ---------------- GraphNorm coeffs ----------------

__global__ __launch_bounds__(256) void k_coeffs(const float* __restrict__ stats,
                                                const float* __restrict__ w, const float* __restrict__ b,
                                                const float* __restrict__ ms,
                                                float* __restrict__ coeffs, int N, int C) {
    int c = threadIdx.x;
    if (c >= C) return;
    float m = stats[c] / (float)N;
    float q = stats[256 + c] / (float)N;
    float msv = ms[c];
    float v = q - m * m * msv * (2.f - msv);
    float sc = w[c] / sqrtf(v + 1e-5f);
    coeffs[c] = sc;
    coeffs[256 + c] = b[c] - sc * m * msv;
}

// leaky(0.2) + GraphNorm affine; reads Yb (fp32, stride 256), writes bf16 at out stride
__global__ __launch_bounds__(256) void k_act(const float* __restrict__ Y, unsigned short* __restrict__ hb,
                                             int ldo, const float* __restrict__ coeffs, int C) {
    int n = blockIdx.x;
    int c = threadIdx.x;
    if (c >= C) return;
    float v = Y[(size_t)n * 256 + c];
    v = v * coeffs[c] + coeffs[256 + c];
    v = (v > 0.f) ? v : 0.2f * v;
    hb[(size_t)n * ldo + c] = f2bf(v);
}

// ---------------- pooling (sorted batch -> segmented run reduction) + head ----------------

__global__ __launch_bounds__(128) void k_pool2(const unsigned short* __restrict__ hb, const int* __restrict__ batch,
                                               float* __restrict__ pooled, float* __restrict__ cntg, int N) {
    int t = threadIdx.x;
    int beg = blockIdx.x * 256;
    int end = beg + 256; if (end > N) end = N;
    int cur = batch[beg];
    float acc = 0.f;
    int runlen = 0;
    for (int n = beg; n < end; n++) {
        int b = batch[n];
        if (b != cur) {
            atomicAdd(&pooled[cur * 128 + t], acc);
            if (t == 0) atomicAdd(&cntg[cur], (float)runlen);
            acc = 0.f; runlen = 0; cur = b;
        }
        acc += bf2f(hb[(size_t)n * 256 + t]);
        runlen++;
    }
    atomicAdd(&pooled[cur * 128 + t], acc);
    if (t == 0) atomicAdd(&cntg[cur], (float)runlen);
}

__global__ __launch_bounds__(128) void k_head(const float* __restrict__ pooled, const float* __restrict__ cntg,
                                              const float* __restrict__ W1, const float* __restrict__ b1,
                                              const float* __restrict__ W2, const float* __restrict__ b2,
                                              float* __restrict__ out) {
    __shared__ float p[128];
    __shared__ float h1[64];
    int g = blockIdx.x;
    int t = threadIdx.x;
    float c = cntg[g];
    if (c < 1.f) c = 1.f;
    p[t] = pooled[g * 128 + t] / c;
    __syncthreads();
    if (t < 64) {
        float s = b1[t];
        for (int i = 0; i < 128; i++) s += p[i] * W1[i * 64 + t];
        h1[t] = tanhf(s);
    }
    __syncthreads();
    if (t < 10) {
        float s = b2[t];
        for (int i = 0; i < 64; i++) s += h1[i] * W2[i * 10 + t];
        out[g * 10 + t] = s;
    }
}

// ---------------- orchestration ----------------

extern "C" void kernel_launch(void* const* d_in, const int* in_sizes, int n_in,
                              void* d_out, int out_size, void* d_ws, size_t ws_size,
                              hipStream_t stream) {
    const float* x = (const float*)d_in[0];
    const int* ei = (const int*)d_in[1];
    const int* batch = (const int*)d_in[2];
    const float* convW[6]; const float* convB[6];
    for (int i = 0; i < 6; i++) { convW[i] = (const float*)d_in[3 + 2 * i]; convB[i] = (const float*)d_in[4 + 2 * i]; }
    const float* bnW[4]; const float* bnB[4]; const float* bnMS[4];
    for (int i = 0; i < 4; i++) { bnW[i] = (const float*)d_in[15 + 3 * i]; bnB[i] = (const float*)d_in[16 + 3 * i]; bnMS[i] = (const float*)d_in[17 + 3 * i]; }
    const float* lin1w = (const float*)d_in[27]; const float* lin1b = (const float*)d_in[28];
    const float* lin2w = (const float*)d_in[29]; const float* lin2b = (const float*)d_in[30];
    float* out = (float*)d_out;

    const int N = in_sizes[0] / 128;
    const int E = in_sizes[1] / 2;
    const int G = out_size / 10;

    struct LayerDef { int K, Cin, Cout, bn; };
    const LayerDef L[6] = {
        {2, 128, 190, 0},
        {2, 190, 256, 1},
        {2, 256, 169, 2},
        {5, 169, 190, -1},
        {1, 190, 256, -1},
        {3, 256, 128, 3},
    };
    const int stride[6] = {512, 512, 512, 1280, 256, 768};

    char* p = (char*)d_ws;
    auto alloc = [&](size_t bytes) -> void* { void* r = (void*)p; p += (bytes + 255) & ~(size_t)255; return r; };
    unsigned short* wide = (unsigned short*)alloc((size_t)N * 1280 * 2);  // all Chebyshev terms, bf16
    float* Yb  = (float*)alloc((size_t)N * 256 * 4);                      // GN-layer GEMM out; doubles as L4->L5 bf16 buf
    float* B1f = (float*)alloc((size_t)N * 192 * 4);                      // fp32 tm2 copies (layer 4)
    float* B2f = (float*)alloc((size_t)N * 192 * 4);
    int2* csr = (int2*)alloc((size_t)E * 8);
    int* row_ptr = (int*)alloc((size_t)(N + 1) * 4);
    int* deg3 = (int*)alloc((size_t)N * 3 * 4);
    int* deg = deg3;
    int* cnt = deg3 + N;
    int* fill = deg3 + 2 * N;
    float* stats = (float*)alloc(512 * 4);
    float* coeffs = (float*)alloc(512 * 4);
    float* pooled = (float*)alloc((size_t)G * 129 * 4);
    float* cntg = pooled + (size_t)G * 128;
    unsigned short* WT[6];
    for (int i = 0; i < 6; i++) WT[i] = (unsigned short*)alloc((size_t)L[i].Cout * L[i].K * 256 * 2);

    hipMemsetAsync(deg3, 0, (size_t)N * 3 * 4, stream);
    k_deg_hist<<<cdiv(E, 256), 256, 0, stream>>>(ei, E, deg, cnt);
    k_scan<<<1, 1024, 0, stream>>>(cnt, row_ptr, N, E);
    k_scatter<<<cdiv(E, 256), 256, 0, stream>>>(ei, E, deg, row_ptr, fill, csr);
    for (int i = 0; i < 6; i++) {
        int ldk = L[i].K * 256;
        int total = L[i].Cout * ldk;
        k_wconv<<<cdiv(total, 256), 256, 0, stream>>>(convW[i], WT[i], L[i].Cin, L[i].Cout, ldk, total);
    }
    k_x0<<<N, 128, 0, stream>>>(x, wide, N);

    const int NB = cdiv(N, PNB);
    auto prop = [&](const unsigned short* in, unsigned short* outb, float* outf,
                    const unsigned short* tm2b, const float* tm2f, int Cin, int ld4) {
        int C4 = cdiv(Cin, 4);
        int nch = cdiv(C4, 16);
        int grid = 8 * cdiv(NB, 8 / nch);
        k_prop_c<<<grid, 256, 0, stream>>>(in, outb, outf, tm2b, tm2f, row_ptr, csr, C4, nch, N, ld4);
    };

    for (int li = 0; li < 6; li++) {
        const int K = L[li].K, Cin = L[li].Cin, Cout = L[li].Cout;
        const int st = stride[li], ld4 = st / 4;
        const unsigned short* src = (li == 4) ? (const unsigned short*)Yb : wide;  // L5 reads Yb-as-bf16

        if (K >= 2)  // T1 = prop(T0)
            prop(src, wide + 256, (li == 3) ? B1f : nullptr, nullptr, nullptr, Cin, ld4);
        if (K >= 3)  // T2 = 2*prop(T1) - T0
            prop(wide + 256, wide + 512, (li == 3) ? B2f : nullptr, wide, nullptr, Cin, ld4);
        if (li == 3) {
            // T3 = 2*prop(T2) - T1 (fp32 tm2 = B1f; overwrite B1f with T3 fp32)
            prop(wide + 512, wide + 768, B1f, nullptr, B1f, Cin, ld4);
            // T4 = 2*prop(T3) - T2 (fp32 tm2 = B2f)
            prop(wide + 768, wide + 1024, nullptr, nullptr, B2f, Cin, ld4);
        }

        const int bnidx = L[li].bn;
        dim3 gg(cdiv(Cout, 128), cdiv(N, 128));
        if (bnidx >= 0) {
            hipMemsetAsync(stats, 0, 512 * 4, stream);
            k_gemm_w<<<gg, 256, 0, stream>>>(src, st, WT[li], convB[li], Yb, stats,
                                             nullptr, 0, N, st, Cout);
            k_coeffs<<<1, 256, 0, stream>>>(stats, bnW[bnidx], bnB[bnidx], bnMS[bnidx], coeffs, N, Cout);
            const int nxt = (li < 5) ? stride[li + 1] : 256;
            k_act<<<N, 256, 0, stream>>>(Yb, wide, nxt, coeffs, Cout);
        } else if (li == 3) {
            // fused ReLU -> Yb-as-bf16 (stride 256) = L5's input; cols 190..255 zero-filled
            k_gemm_w<<<gg, 256, 0, stream>>>(wide, st, WT[li], convB[li], nullptr, nullptr,
                                             (unsigned short*)Yb, 256, N, st, Cout);
        } else {
            // li==4: fused ReLU -> wide (stride 768) = L6's T0 (reads Yb, writes wide: no alias)
            k_gemm_w<<<gg, 256, 0, stream>>>((const unsigned short*)Yb, st, WT[li], convB[li],
                                             nullptr, nullptr, wide, stride[5], N, st, Cout);
        }
    }

    hipMemsetAsync(pooled, 0, (size_t)G * 129 * 4, stream);
    k_pool2<<<cdiv(N, 256), 128, 0, stream>>>(wide, batch, pooled, cntg, N);
    k_head<<<G, 128, 0, stream>>>(pooled, cntg, lin1w, lin1b, lin2w, lin2b, out);
}